// Round 1
// baseline (1219.641 us; speedup 1.0000x reference)
//
#include <hip/hip_runtime.h>
#include <math.h>

#define B_   64
#define H_   32
#define KVH_ 8
#define D_   128
#define BS_  128
#define BPS_ 16
#define NB_  1024
#define G_   4
#define SCALE_ 0.08838834764831845f
#define PAD_ 132   // 128 + 4 floats: conflict-free-ish padded K rows

__global__ void append_kv_kernel(const float* __restrict__ knew,
                                 const float* __restrict__ vnew,
                                 float* __restrict__ kc,
                                 float* __restrict__ vc,
                                 const int* __restrict__ bidx,
                                 const int* __restrict__ boff) {
  int t = blockIdx.x * blockDim.x + threadIdx.x;
  if (t >= B_ * KVH_ * D_) return;
  int b   = t / (KVH_ * D_);
  int rem = t - b * (KVH_ * D_);
  long dst = (long)bidx[b] * (BS_ * KVH_ * D_) + (long)boff[b] * (KVH_ * D_) + rem;
  kc[dst] = knew[t];
  vc[dst] = vnew[t];
}

// one workgroup per (seq b, kv-head): flash-decode over 16 KV blocks
__launch_bounds__(1024, 8)
__global__ void paged_attn_kernel(const float* __restrict__ query,
                                  const float* __restrict__ kc,
                                  const float* __restrict__ vc,
                                  const int* __restrict__ block_list,
                                  const float* __restrict__ bias,
                                  float* __restrict__ out) {
  __shared__ float kbuf[BS_ * PAD_];     // 67584 B, K tile (reused as epilogue scratch)
  __shared__ float qs[G_ * D_];          // scaled queries, 4 heads
  __shared__ float spart[2 * G_ * BS_];  // half-dot partials [h][g][slot]
  __shared__ float sl[G_ * BS_];         // combined scores
  __shared__ float pl[G_ * BS_];         // exp probs
  __shared__ float redm[8];
  __shared__ float reds[8];
  __shared__ float Msh[G_], Lsh[G_], Ash[G_];

  const int tid = threadIdx.x;
  const int bid = blockIdx.x;
  const int kvh = bid & (KVH_ - 1);
  const int b   = bid >> 3;

  if (tid < G_ * D_) qs[tid] = query[(long)b * (H_ * D_) + kvh * (G_ * D_) + tid] * SCALE_;
  if (tid < G_) { Msh[tid] = -INFINITY; Lsh[tid] = 0.f; Ash[tid] = 0.f; }

  float acc[G_][2];
  #pragma unroll
  for (int g = 0; g < G_; g++) { acc[g][0] = 0.f; acc[g][1] = 0.f; }

  const int d2    = (tid & 63) * 2;   // PV: d-pair owned by this thread
  const int chunk = tid >> 6;         // PV: slot-chunk 0..15 (wave-uniform)
  const int slot  = tid & 127;        // score: slot
  const int gg    = (tid >> 7) & 3;   // score: head-in-group (wave-uniform)
  const int hh    = tid >> 9;         // score: d-half

  __syncthreads();

  for (int j = 0; j < BPS_; j++) {
    const int  n  = b * BPS_ + j;
    const int  c  = block_list[n];
    const long kb = (long)c * (BS_ * KVH_ * D_) + kvh * D_;

    // ---- stage K tile (128 slots x 128 d) into padded LDS, coalesced float4 ----
    {
      float4 tmp[4];
      const int r0 = tid >> 5;
      const int dd = (tid & 31) << 2;
      #pragma unroll
      for (int i = 0; i < 4; i++) {
        int row = i * 32 + r0;
        tmp[i] = *reinterpret_cast<const float4*>(kc + kb + (long)row * (KVH_ * D_) + dd);
      }
      #pragma unroll
      for (int i = 0; i < 4; i++) {
        int row = i * 32 + r0;
        *reinterpret_cast<float4*>(kbuf + row * PAD_ + dd) = tmp[i];
      }
    }
    __syncthreads();

    // ---- scores: thread = (slot, g, d-half); K rows b128, q broadcast ----
    {
      const float* kr = kbuf + slot * PAD_ + hh * 64;
      const float* qr = qs + gg * D_ + hh * 64;
      float s = 0.f;
      #pragma unroll
      for (int i = 0; i < 16; i++) {
        float4 k4 = *reinterpret_cast<const float4*>(kr + 4 * i);
        float4 q4 = *reinterpret_cast<const float4*>(qr + 4 * i);
        s = fmaf(k4.x, q4.x, s); s = fmaf(k4.y, q4.y, s);
        s = fmaf(k4.z, q4.z, s); s = fmaf(k4.w, q4.w, s);
      }
      spart[tid] = s;
    }
    __syncthreads();

    // ---- combine halves + bias, per-g block max (wave shuffle) ----
    if (tid < 512) {
      float s = spart[tid] + spart[512 + tid] + bias[(long)n * BS_ + slot];
      sl[tid] = s;
      float m = s;
      #pragma unroll
      for (int off = 32; off; off >>= 1) m = fmaxf(m, __shfl_xor(m, off));
      if ((tid & 63) == 0) redm[tid >> 6] = m;
    }
    __syncthreads();
    if (tid < G_) {
      float mj   = fmaxf(redm[2 * tid], redm[2 * tid + 1]);
      float Mold = Msh[tid];
      float Mnew = fmaxf(Mold, mj);
      Ash[tid] = __expf(Mold - Mnew);   // first block: exp(-inf)=0
      Msh[tid] = Mnew;
    }
    __syncthreads();
    if (tid < 512) {
      float p = __expf(sl[tid] - Msh[gg]);
      pl[tid] = p;
      #pragma unroll
      for (int off = 32; off; off >>= 1) p += __shfl_xor(p, off);
      if ((tid & 63) == 0) reds[tid >> 6] = p;
    }
    __syncthreads();
    if (tid < G_) {
      Lsh[tid] = Lsh[tid] * Ash[tid] + reds[2 * tid] + reds[2 * tid + 1];
    }

    // ---- PV: V streamed straight from global (coalesced float2), online rescale ----
    {
      float a0 = Ash[0], a1 = Ash[1], a2 = Ash[2], a3 = Ash[3];
      acc[0][0] *= a0; acc[0][1] *= a0;
      acc[1][0] *= a1; acc[1][1] *= a1;
      acc[2][0] *= a2; acc[2][1] *= a2;
      acc[3][0] *= a3; acc[3][1] *= a3;
      #pragma unroll
      for (int i = 0; i < 8; i++) {
        int sidx = chunk * 8 + i;
        float2 v2 = *reinterpret_cast<const float2*>(vc + kb + (long)sidx * (KVH_ * D_) + d2);
        float p0 = pl[sidx], p1 = pl[128 + sidx], p2 = pl[256 + sidx], p3 = pl[384 + sidx];
        acc[0][0] = fmaf(p0, v2.x, acc[0][0]); acc[0][1] = fmaf(p0, v2.y, acc[0][1]);
        acc[1][0] = fmaf(p1, v2.x, acc[1][0]); acc[1][1] = fmaf(p1, v2.y, acc[1][1]);
        acc[2][0] = fmaf(p2, v2.x, acc[2][0]); acc[2][1] = fmaf(p2, v2.y, acc[2][1]);
        acc[3][0] = fmaf(p3, v2.x, acc[3][0]); acc[3][1] = fmaf(p3, v2.y, acc[3][1]);
      }
    }
    __syncthreads();
  }

  // ---- epilogue: reduce 16 slot-chunks per (g,d), divide by L, store ----
  {
    float* part = kbuf;   // reuse K tile buffer
    #pragma unroll
    for (int g = 0; g < G_; g++) {
      part[(g * 128 + d2) * 17 + chunk]     = acc[g][0];
      part[(g * 128 + d2 + 1) * 17 + chunk] = acc[g][1];
    }
    __syncthreads();
    if (tid < 512) {
      float ssum = 0.f;
      #pragma unroll
      for (int ch = 0; ch < 16; ch++) ssum += part[tid * 17 + ch];
      float denom = fmaxf(Lsh[gg], 1e-37f);
      out[(long)b * (H_ * D_) + kvh * (G_ * D_) + tid] = ssum / denom;
    }
  }
}

extern "C" void kernel_launch(void* const* d_in, const int* in_sizes, int n_in,
                              void* d_out, int out_size, void* d_ws, size_t ws_size,
                              hipStream_t stream) {
  const float* query = (const float*)d_in[0];
  const float* knew  = (const float*)d_in[1];
  const float* vnew  = (const float*)d_in[2];
  float* kcache      = (float*)d_in[3];   // harness restores inputs each launch
  float* vcache      = (float*)d_in[4];
  const int*   block_list = (const int*)d_in[5];
  // d_in[6] block_groups, d_in[7] block_mapping: implied by block layout
  const float* bias  = (const float*)d_in[8];
  const int*   bidx  = (const int*)d_in[9];
  const int*   boff  = (const int*)d_in[10];

  append_kv_kernel<<<(B_ * KVH_ * D_ + 255) / 256, 256, 0, stream>>>(
      knew, vnew, kcache, vcache, bidx, boff);
  paged_attn_kernel<<<B_ * KVH_, 1024, 0, stream>>>(
      query, kcache, vcache, block_list, bias, (float*)d_out);
}